// Round 5
// baseline (2267.239 us; speedup 1.0000x reference)
//
#include <hip/hip_runtime.h>
#include <hip/hip_bf16.h>
#include <stdint.h>

#define N_NODESC 50000
#define NPAD     50048   // padded to multiple of 128 (and 64)
#define N_EDGESC 800000
#define DIM      256
#define DIM3     768
#define NSTEPS   5
#define NGRAPH   64

typedef __attribute__((ext_vector_type(4))) float  f32x4;
typedef __attribute__((ext_vector_type(8))) short  short8;
typedef __attribute__((ext_vector_type(4))) unsigned short u16x4;

// ---------------- device-global scratch (no d_ws dependence) ----------------
__device__ float          g_hf[(size_t)NPAD * DIM];
__device__ unsigned short g_hb[(size_t)NPAD * DIM];
__device__ unsigned short g_p [(size_t)NPAD * DIM3];
__device__ unsigned short g_a [(size_t)NPAD * DIM];
__device__ unsigned short g_Wc[DIM * DIM3];
__device__ unsigned short g_WI[DIM3 * DIM];   // interleaved: c = 48j + g*16 + f  <->  row g*256+16j+f
__device__ unsigned short g_WH[DIM3 * DIM];   // same interleave
__device__ int            g_cnt[NPAD * 4];
__device__ int            g_rowoff[N_NODESC + 1];
__device__ int            g_cur[N_NODESC];
__device__ unsigned       g_eidx[N_EDGESC];
__device__ int            g_bsum[256];
__device__ int            g_boff[256];
__device__ float          g_gate[N_NODESC];
__device__ int            g_soff[NGRAPH + 1];
__device__ float          g_gmax[NGRAPH];
__device__ float          g_gden[NGRAPH];

__device__ __forceinline__ float bf2f(unsigned short u) {
  unsigned x = ((unsigned)u) << 16;
  return __builtin_bit_cast(float, x);
}
__device__ __forceinline__ unsigned short f2bf(float f) {
  unsigned u = __builtin_bit_cast(unsigned, f);
  u += 0x7fffu + ((u >> 16) & 1u);
  return (unsigned short)(u >> 16);
}
__device__ __forceinline__ float sigm(float x) { return 1.0f / (1.0f + expf(-x)); }

__device__ __forceinline__ void async16(const void* g, void* l) {
  __builtin_amdgcn_global_load_lds(
      (const __attribute__((address_space(1))) unsigned int*)g,
      (__attribute__((address_space(3))) unsigned int*)l, 16, 0, 0);
}

// ---------------- once-per-launch prep ----------------

__global__ void k_zero_cnt() {
  int i = blockIdx.x * 256 + threadIdx.x;   // NPAD*4 = 200192 = 782*256
  g_cnt[i] = 0;
}

// Wc[f][e*256+d] = W_msg[e][d][f].
// WI/WH interleaved for the fused GRU kernel: index t = c*256+k with
// c = 48j + g*16 + f  maps to original row (g*256 + 16j + f).
__global__ void k_prep_w(const float* __restrict__ Wmsg, const float* __restrict__ wih,
                         const float* __restrict__ whh) {
  int i = blockIdx.x * 256 + threadIdx.x;
  if (i < 196608) {
    int f = i / 768, j = i - f * 768;      // j = e*256 + d
    int e = j >> 8, d = j & 255;
    g_Wc[i] = f2bf(Wmsg[(e << 16) + (d << 8) + f]);
  } else if (i < 393216) {
    int t = i - 196608;
    int c = t >> 8, k = t & 255;
    int j = c / 48, rem = c - j * 48, g = rem >> 4, f = rem & 15;
    g_WI[t] = f2bf(wih[(g * 256 + j * 16 + f) * 256 + k]);
  } else if (i < 589824) {
    int t = i - 393216;
    int c = t >> 8, k = t & 255;
    int j = c / 48, rem = c - j * 48, g = rem >> 4, f = rem & 15;
    g_WH[t] = f2bf(whh[(g * 256 + j * 16 + f) * 256 + k]);
  }
}

__global__ void k_embed(const int* __restrict__ x, const float* __restrict__ emb) {
  int i = blockIdx.x * 256 + threadIdx.x;        // N_NODESC*64 total
  int n = i >> 6, t = i & 63;
  if (n >= N_NODESC) return;
  float4 v = *(const float4*)(emb + (size_t)x[n] * DIM + t * 4);
  *(float4*)(g_hf + (size_t)n * DIM + t * 4) = v;
  u16x4 b = {f2bf(v.x), f2bf(v.y), f2bf(v.z), f2bf(v.w)};
  *(u16x4*)(g_hb + (size_t)n * DIM + t * 4) = b;
}

__global__ void k_count(const int* __restrict__ dst, const int* __restrict__ et) {
  int e = blockIdx.x * 256 + threadIdx.x;
  if (e >= N_EDGESC) return;
  atomicAdd(&g_cnt[dst[e] * 4 + et[e]], 1);
}

__global__ void k_scan1() {
  __shared__ int lds[256];
  int n = blockIdx.x * 256 + threadIdx.x;
  int deg = (n < N_NODESC) ? (g_cnt[n * 4] + g_cnt[n * 4 + 1] + g_cnt[n * 4 + 2]) : 0;
  lds[threadIdx.x] = deg;
  __syncthreads();
  for (int o = 128; o > 0; o >>= 1) {
    if (threadIdx.x < o) lds[threadIdx.x] += lds[threadIdx.x + o];
    __syncthreads();
  }
  if (threadIdx.x == 0) g_bsum[blockIdx.x] = lds[0];
}

__global__ void k_scan2() {
  __shared__ int lds[256];
  int t = threadIdx.x;
  int v = (t < 196) ? g_bsum[t] : 0;
  lds[t] = v;
  __syncthreads();
  for (int o = 1; o < 256; o <<= 1) {
    int u = (t >= o) ? lds[t - o] : 0;
    __syncthreads();
    lds[t] += u;
    __syncthreads();
  }
  if (t < 196) g_boff[t] = lds[t] - v;   // exclusive
}

__global__ void k_scan3() {
  __shared__ int lds[256];
  int n = blockIdx.x * 256 + threadIdx.x;
  int t = threadIdx.x;
  int deg = (n < N_NODESC) ? (g_cnt[n * 4] + g_cnt[n * 4 + 1] + g_cnt[n * 4 + 2]) : 0;
  lds[t] = deg;
  __syncthreads();
  for (int o = 1; o < 256; o <<= 1) {
    int u = (t >= o) ? lds[t - o] : 0;
    __syncthreads();
    lds[t] += u;
    __syncthreads();
  }
  if (n < N_NODESC) {
    int off = g_boff[blockIdx.x] + lds[t] - deg;
    g_rowoff[n] = off;
    g_cur[n] = off;
  }
  if (n == N_NODESC - 1) g_rowoff[N_NODESC] = g_boff[blockIdx.x] + lds[t];
}

__global__ void k_fill(const int* __restrict__ src, const int* __restrict__ dst,
                       const int* __restrict__ et) {
  int e = blockIdx.x * 256 + threadIdx.x;
  if (e >= N_EDGESC) return;
  int p = atomicAdd(&g_cur[dst[e]], 1);
  g_eidx[p] = (((unsigned)src[e]) << 2) | (unsigned)et[e];
}

__global__ void k_segoff(const int* __restrict__ seg) {
  int n = blockIdx.x * 256 + threadIdx.x;
  if (n >= N_NODESC) return;
  int g = seg[n];
  int gp = (n == 0) ? -1 : seg[n - 1];
  for (int t = gp + 1; t <= g; ++t) g_soff[t] = n;
  if (n == N_NODESC - 1)
    for (int t = g + 1; t <= NGRAPH; ++t) g_soff[t] = N_NODESC;
}

// ---------------- per-step kernels ----------------

#define ACC_ET(hv, et)                                                        \
  {                                                                           \
    float x0 = bf2f(hv[0]), x1 = bf2f(hv[1]), x2 = bf2f(hv[2]), x3 = bf2f(hv[3]); \
    if (et == 0)      { a0[0] += x0; a0[1] += x1; a0[2] += x2; a0[3] += x3; } \
    else if (et == 1) { a1[0] += x0; a1[1] += x1; a1[2] += x2; a1[3] += x3; } \
    else              { a2[0] += x0; a2[1] += x1; a2[2] += x2; a2[3] += x3; } \
  }

// p[n, e*256+d] = sum over in-edges of type e of h_bf16[src, d]; one wave per node.
// Edge loop unrolled x4 so 4 independent 512B gathers are in flight per wave.
__global__ __launch_bounds__(256) void k_agg() {
  int node = blockIdx.x * 4 + (threadIdx.x >> 6);
  int lane = threadIdx.x & 63;
  if (node >= N_NODESC) return;
  float a0[4] = {0.f, 0.f, 0.f, 0.f};
  float a1[4] = {0.f, 0.f, 0.f, 0.f};
  float a2[4] = {0.f, 0.f, 0.f, 0.f};
  int s = g_rowoff[node], e = g_rowoff[node + 1];
  int i = s;
  for (; i + 4 <= e; i += 4) {
    unsigned v0 = g_eidx[i], v1 = g_eidx[i + 1], v2 = g_eidx[i + 2], v3 = g_eidx[i + 3];
    u16x4 hv0 = *(const u16x4*)(g_hb + (size_t)(v0 >> 2) * DIM + lane * 4);
    u16x4 hv1 = *(const u16x4*)(g_hb + (size_t)(v1 >> 2) * DIM + lane * 4);
    u16x4 hv2 = *(const u16x4*)(g_hb + (size_t)(v2 >> 2) * DIM + lane * 4);
    u16x4 hv3 = *(const u16x4*)(g_hb + (size_t)(v3 >> 2) * DIM + lane * 4);
    int e0 = (int)(v0 & 3u), e1 = (int)(v1 & 3u), e2 = (int)(v2 & 3u), e3 = (int)(v3 & 3u);
    ACC_ET(hv0, e0);
    ACC_ET(hv1, e1);
    ACC_ET(hv2, e2);
    ACC_ET(hv3, e3);
  }
  for (; i < e; ++i) {
    unsigned v = g_eidx[i];
    u16x4 hv = *(const u16x4*)(g_hb + (size_t)(v >> 2) * DIM + lane * 4);
    int et = (int)(v & 3u);
    ACC_ET(hv, et);
  }
  size_t base = (size_t)node * DIM3 + lane * 4;
  u16x4 o0 = {f2bf(a0[0]), f2bf(a0[1]), f2bf(a0[2]), f2bf(a0[3])};
  u16x4 o1 = {f2bf(a1[0]), f2bf(a1[1]), f2bf(a1[2]), f2bf(a1[3])};
  u16x4 o2 = {f2bf(a2[0]), f2bf(a2[1]), f2bf(a2[2]), f2bf(a2[3])};
  *(u16x4*)(g_p + base)       = o0;
  *(u16x4*)(g_p + base + 256) = o1;
  *(u16x4*)(g_p + base + 512) = o2;
}

// g_a[bf16, NPADx256] = g_p[NPADx768] @ g_Wc^T + cnt*b_msg   (unchanged m97-style)
__global__ __launch_bounds__(256) void k_gemm0(const float* __restrict__ bmsg) {
  constexpr int K = DIM3;
  constexpr int NC = DIM;
  const unsigned short* __restrict__ A  = g_p;
  const unsigned short* __restrict__ BT = g_Wc;

  __shared__ unsigned short lA[128 * 32];
  __shared__ unsigned short lB[128 * 32];
  const int tx = threadIdx.x;
  const int lane = tx & 63;
  const int wave = tx >> 6;
  const int wr = wave >> 1, wc = wave & 1;
  const int tileN = blockIdx.x * 128;
  const int tileM = blockIdx.y * 128;

  f32x4 acc[4][4];
#pragma unroll
  for (int m = 0; m < 4; ++m)
#pragma unroll
    for (int n = 0; n < 4; ++n) {
      acc[m][n][0] = 0.f; acc[m][n][1] = 0.f; acc[m][n][2] = 0.f; acc[m][n][3] = 0.f;
    }

  const int r0 = tx >> 2;
  const int c0 = (tx & 3) * 8;

  for (int k0 = 0; k0 < K; k0 += 32) {
#pragma unroll
    for (int i = 0; i < 2; ++i) {
      int row = i * 64 + r0;
      async16((const void*)(A + (size_t)(tileM + row) * K + k0 + c0),
              (void*)(lA + row * 32 + c0));
    }
#pragma unroll
    for (int i = 0; i < 2; ++i) {
      int row = i * 64 + r0;
      async16((const void*)(BT + (size_t)(tileN + row) * K + k0 + c0),
              (void*)(lB + row * 32 + c0));
    }
    __syncthreads();
    short8 af[4], bfr[4];
#pragma unroll
    for (int m = 0; m < 4; ++m)
      af[m] = *(const short8*)(lA + (wr * 64 + m * 16 + (lane & 15)) * 32 + (lane >> 4) * 8);
#pragma unroll
    for (int n = 0; n < 4; ++n)
      bfr[n] = *(const short8*)(lB + (wc * 64 + n * 16 + (lane & 15)) * 32 + (lane >> 4) * 8);
#pragma unroll
    for (int m = 0; m < 4; ++m)
#pragma unroll
      for (int n = 0; n < 4; ++n)
        acc[m][n] = __builtin_amdgcn_mfma_f32_16x16x32_bf16(af[m], bfr[n], acc[m][n], 0, 0, 0);
    __syncthreads();
  }

#pragma unroll
  for (int m = 0; m < 4; ++m) {
    int row0 = tileM + wr * 64 + m * 16 + (lane >> 4) * 4;
#pragma unroll
    for (int n = 0; n < 4; ++n) {
      int col = tileN + wc * 64 + n * 16 + (lane & 15);
      f32x4 v = acc[m][n];
#pragma unroll
      for (int r = 0; r < 4; ++r) {
        int row = row0 + r;
        const int* c = g_cnt + (size_t)row * 4;
        float val = v[r] + c[0] * bmsg[col] + c[1] * bmsg[256 + col] + c[2] * bmsg[512 + col];
        g_a[(size_t)row * NC + col] = f2bf(val);
      }
    }
  }
}

// Fused (a@WI^T) + (h@WH^T) + GRU elementwise -> h' (f32 + bf16), in place.
// 64 rows/block, full K=256 in LDS (XOR-swizzled both-sides), weights from L2.
// Wave w handles dim-groups j in {w, w+4, w+8, w+12}; per group: 3 col-frags
// [r|z|n] of the interleaved weights give complete GRU gates for 16 dims.
__global__ __launch_bounds__(256) void k_fused(const float* __restrict__ bih,
                                               const float* __restrict__ bhh) {
  __shared__ unsigned short lAa[64 * 256];   // 32 KB
  __shared__ unsigned short lAh[64 * 256];   // 32 KB
  const int tx = threadIdx.x;
  const int lane = tx & 63;
  const int wave = tx >> 6;
  const int tileM = blockIdx.x * 64;

  // Stage both A-tiles. LDS dest linear; global source pre-swizzled:
  // physical 16B slot s of row holds global chunk (s ^ (row&7)).
#pragma unroll
  for (int it = 0; it < 8; ++it) {
    int o = it * 4096 + tx * 16;          // LDS byte offset (wave-contiguous)
    int row = o >> 9;
    int s = (o >> 4) & 31;
    int cg = s ^ (row & 7);
    int gelem = (tileM + row) * 256 + cg * 8;
    async16((const void*)(g_a + gelem), (void*)((char*)lAa + o));
    async16((const void*)(g_hb + gelem), (void*)((char*)lAh + o));
  }
  __syncthreads();

  const int f = lane & 15;
  const int q = lane >> 4;                 // 0..3
  const int xr = f & 7;

  for (int t = 0; t < 4; ++t) {
    int j = wave + t * 4;                  // dim-group 0..15 (dims 16j..16j+15)
    f32x4 acc[4][4];                       // [m][0]=r-sum [1]=z-sum [2]=i_n [3]=h_n
#pragma unroll
    for (int m = 0; m < 4; ++m)
#pragma unroll
      for (int n = 0; n < 4; ++n) {
        acc[m][n][0] = 0.f; acc[m][n][1] = 0.f; acc[m][n][2] = 0.f; acc[m][n][3] = 0.f;
      }
    const unsigned short* WIb = g_WI + (size_t)(48 * j + f) * 256;
    const unsigned short* WHb = g_WH + (size_t)(48 * j + f) * 256;

    for (int kk = 0; kk < 8; ++kk) {
      short8 aa[4], ah[4];
#pragma unroll
      for (int m = 0; m < 4; ++m) {
        int boff = (m * 16 + f) * 512 + (((kk * 4 + q) ^ xr) * 16);
        aa[m] = *(const short8*)((const char*)lAa + boff);
        ah[m] = *(const short8*)((const char*)lAh + boff);
      }
      int koff = kk * 32 + q * 8;
      short8 bi0 = *(const short8*)(WIb + 0 * 4096 + koff);
      short8 bi1 = *(const short8*)(WIb + 1 * 4096 + koff);
      short8 bi2 = *(const short8*)(WIb + 2 * 4096 + koff);
      short8 bh0 = *(const short8*)(WHb + 0 * 4096 + koff);
      short8 bh1 = *(const short8*)(WHb + 1 * 4096 + koff);
      short8 bh2 = *(const short8*)(WHb + 2 * 4096 + koff);
#pragma unroll
      for (int m = 0; m < 4; ++m) {
        acc[m][0] = __builtin_amdgcn_mfma_f32_16x16x32_bf16(aa[m], bi0, acc[m][0], 0, 0, 0);
        acc[m][0] = __builtin_amdgcn_mfma_f32_16x16x32_bf16(ah[m], bh0, acc[m][0], 0, 0, 0);
        acc[m][1] = __builtin_amdgcn_mfma_f32_16x16x32_bf16(aa[m], bi1, acc[m][1], 0, 0, 0);
        acc[m][1] = __builtin_amdgcn_mfma_f32_16x16x32_bf16(ah[m], bh1, acc[m][1], 0, 0, 0);
        acc[m][2] = __builtin_amdgcn_mfma_f32_16x16x32_bf16(aa[m], bi2, acc[m][2], 0, 0, 0);
        acc[m][3] = __builtin_amdgcn_mfma_f32_16x16x32_bf16(ah[m], bh2, acc[m][3], 0, 0, 0);
      }
    }

    int d = j * 16 + f;
    float biR = bih[d] + bhh[d];
    float biZ = bih[256 + d] + bhh[256 + d];
    float biN = bih[512 + d];
    float bhN = bhh[512 + d];
#pragma unroll
    for (int m = 0; m < 4; ++m) {
      int row0 = tileM + m * 16 + q * 4;
#pragma unroll
      for (int r = 0; r < 4; ++r) {
        int row = row0 + r;
        float rr = sigm(acc[m][0][r] + biR);
        float zz = sigm(acc[m][1][r] + biZ);
        float nn = tanhf(acc[m][2][r] + biN + rr * (acc[m][3][r] + bhN));
        float ho = g_hf[(size_t)row * DIM + d];
        float o = (1.f - zz) * nn + zz * ho;
        g_hf[(size_t)row * DIM + d] = o;
        g_hb[(size_t)row * DIM + d] = f2bf(o);
      }
    }
  }
}

// ---------------- pooling ----------------

__global__ void k_gate(const float* __restrict__ gw, const float* __restrict__ gb) {
  int node = blockIdx.x * 4 + (threadIdx.x >> 6);
  int lane = threadIdx.x & 63;
  if (node >= N_NODESC) return;
  float4 h = *(const float4*)(g_hf + (size_t)node * DIM + lane * 4);
  float4 w = *(const float4*)(gw + lane * 4);
  float p = h.x * w.x + h.y * w.y + h.z * w.z + h.w * w.w;
  for (int o = 32; o > 0; o >>= 1) p += __shfl_xor(p, o);
  if (lane == 0) g_gate[node] = p + gb[0];
}

// Per-graph softmax max + denom (gate array is only 200 KB; 64 blocks).
__global__ void k_segred() {
  int g = blockIdx.x, t = threadIdx.x;
  __shared__ float red[256];
  int s = g_soff[g], e = g_soff[g + 1];
  float m = -3.4e38f;
  for (int n = s + t; n < e; n += 256) m = fmaxf(m, g_gate[n]);
  red[t] = m;
  __syncthreads();
  for (int o = 128; o > 0; o >>= 1) {
    if (t < o) red[t] = fmaxf(red[t], red[t + o]);
    __syncthreads();
  }
  m = red[0];
  __syncthreads();
  float sm = 0.f;
  for (int n = s + t; n < e; n += 256) sm += expf(g_gate[n] - m);
  red[t] = sm;
  __syncthreads();
  for (int o = 128; o > 0; o >>= 1) {
    if (t < o) red[t] += red[t + o];
    __syncthreads();
  }
  if (t == 0) {
    g_gmax[g] = m;
    g_gden[g] = (e > s && red[0] != 0.f) ? red[0] : 1.f;
  }
}

__global__ void k_zero_out(float* __restrict__ out) {
  out[blockIdx.x * 256 + threadIdx.x] = 0.f;   // 64*256 = NGRAPH*DIM
}

// 391 blocks x 128 nodes; thread t owns output dim t. seg_ids sorted ->
// accumulate and flush on graph boundary with one atomicAdd per (block,graph).
__global__ __launch_bounds__(256) void k_poolacc(const int* __restrict__ seg,
                                                 float* __restrict__ out) {
  __shared__ int   segL[128];
  __shared__ float alphaL[128];
  int base = blockIdx.x * 128;
  int t = threadIdx.x;
  if (t < 128) {
    int n = base + t;
    if (n < N_NODESC) {
      int g = seg[n];
      segL[t] = g;
      alphaL[t] = expf(g_gate[n] - g_gmax[g]) / g_gden[g];
    } else {
      segL[t] = -1;
    }
  }
  __syncthreads();
  float acc = 0.f;
  int gcur = segL[0];
  for (int j = 0; j < 128; ++j) {
    int gs = segL[j];
    if (gs < 0) break;
    if (gs != gcur) {
      atomicAdd(out + (size_t)gcur * DIM + t, acc);
      acc = 0.f;
      gcur = gs;
    }
    acc += alphaL[j] * g_hf[(size_t)(base + j) * DIM + t];
  }
  if (gcur >= 0) atomicAdd(out + (size_t)gcur * DIM + t, acc);
}

// ---------------- launch ----------------

extern "C" void kernel_launch(void* const* d_in, const int* in_sizes, int n_in,
                              void* d_out, int out_size, void* d_ws, size_t ws_size,
                              hipStream_t stream) {
  const int* x = (const int*)d_in[0];
  const int* src = (const int*)d_in[1];
  const int* dst = (const int*)d_in[2];
  const int* ety = (const int*)d_in[3];
  const int* seg = (const int*)d_in[4];
  const float* emb = (const float*)d_in[6];
  const float* Wmsg = (const float*)d_in[7];
  const float* bmsg = (const float*)d_in[8];
  const float* wih = (const float*)d_in[9];
  const float* whh = (const float*)d_in[10];
  const float* bih = (const float*)d_in[11];
  const float* bhh = (const float*)d_in[12];
  const float* gw = (const float*)d_in[13];
  const float* gb = (const float*)d_in[14];
  float* out = (float*)d_out;

  k_zero_cnt<<<NPAD * 4 / 256, 256, 0, stream>>>();
  k_prep_w<<<2304, 256, 0, stream>>>(Wmsg, wih, whh);
  k_embed<<<12500, 256, 0, stream>>>(x, emb);
  k_count<<<(N_EDGESC + 255) / 256, 256, 0, stream>>>(dst, ety);
  k_scan1<<<196, 256, 0, stream>>>();
  k_scan2<<<1, 256, 0, stream>>>();
  k_scan3<<<196, 256, 0, stream>>>();
  k_fill<<<(N_EDGESC + 255) / 256, 256, 0, stream>>>(src, dst, ety);
  k_segoff<<<196, 256, 0, stream>>>(seg);

  for (int s = 0; s < NSTEPS; ++s) {
    k_agg<<<12500, 256, 0, stream>>>();
    k_gemm0<<<dim3(2, 391), 256, 0, stream>>>(bmsg);
    k_fused<<<NPAD / 64, 256, 0, stream>>>(bih, bhh);
  }

  k_gate<<<12500, 256, 0, stream>>>(gw, gb);
  k_segred<<<NGRAPH, 256, 0, stream>>>();
  k_zero_out<<<NGRAPH, 256, 0, stream>>>(out);
  k_poolacc<<<391, 256, 0, stream>>>(seg, out);
}

// Round 6
// 1575.640 us; speedup vs baseline: 1.4389x; 1.4389x over previous
//
#include <hip/hip_runtime.h>
#include <hip/hip_bf16.h>
#include <stdint.h>

#define N_NODESC 50000
#define NPAD     50048   // padded to multiple of 128
#define N_EDGESC 800000
#define DIM      256
#define DIM3     768
#define NSTEPS   5
#define NGRAPH   64

typedef __attribute__((ext_vector_type(4))) float  f32x4;
typedef __attribute__((ext_vector_type(8))) short  short8;
typedef __attribute__((ext_vector_type(4))) unsigned short u16x4;
typedef __attribute__((ext_vector_type(4))) _Float16 f16x4;

// ---------------- device-global scratch (no d_ws dependence) ----------------
__device__ float          g_hf[(size_t)NPAD * DIM];
__device__ unsigned short g_hb[(size_t)NPAD * DIM];
__device__ unsigned short g_p [(size_t)NPAD * DIM3];
__device__ unsigned short g_a [(size_t)NPAD * DIM];
__device__ _Float16       g_gi[(size_t)NPAD * DIM3];
__device__ _Float16       g_gh[(size_t)NPAD * DIM3];
__device__ unsigned short g_Wc[DIM * DIM3];
__device__ unsigned short g_WI[DIM3 * DIM];
__device__ unsigned short g_WH[DIM3 * DIM];
__device__ int            g_cnt[NPAD * 4];
__device__ int            g_rowoff[N_NODESC + 1];
__device__ int            g_cur[N_NODESC];
__device__ unsigned       g_eidx[N_EDGESC];
__device__ int            g_bsum[256];
__device__ int            g_boff[256];
__device__ float          g_gate[N_NODESC];
__device__ int            g_soff[NGRAPH + 1];
__device__ float          g_gmax[NGRAPH];
__device__ float          g_gden[NGRAPH];

__device__ __forceinline__ float bf2f(unsigned short u) {
  unsigned x = ((unsigned)u) << 16;
  return __builtin_bit_cast(float, x);
}
__device__ __forceinline__ unsigned short f2bf(float f) {
  unsigned u = __builtin_bit_cast(unsigned, f);
  u += 0x7fffu + ((u >> 16) & 1u);
  return (unsigned short)(u >> 16);
}
__device__ __forceinline__ float sigm(float x) { return 1.0f / (1.0f + expf(-x)); }

__device__ __forceinline__ void async16(const void* g, void* l) {
  __builtin_amdgcn_global_load_lds(
      (const __attribute__((address_space(1))) unsigned int*)g,
      (__attribute__((address_space(3))) unsigned int*)l, 16, 0, 0);
}

// ---------------- once-per-launch prep ----------------

__global__ void k_zero_cnt() {
  int i = blockIdx.x * 256 + threadIdx.x;   // NPAD*4 = 200192 = 782*256
  g_cnt[i] = 0;
}

// Wc[f][e*256+d] = W_msg[e][d][f]; WI = w_ih (already [j][d]); WH = w_hh. All bf16.
__global__ void k_prep_w(const float* __restrict__ Wmsg, const float* __restrict__ wih,
                         const float* __restrict__ whh) {
  int i = blockIdx.x * 256 + threadIdx.x;
  if (i < 196608) {
    int f = i / 768, j = i - f * 768;      // j = e*256 + d
    int e = j >> 8, d = j & 255;
    g_Wc[i] = f2bf(Wmsg[(e << 16) + (d << 8) + f]);
  } else if (i < 393216) {
    int t = i - 196608;
    g_WI[t] = f2bf(wih[t]);
  } else if (i < 589824) {
    int t = i - 393216;
    g_WH[t] = f2bf(whh[t]);
  }
}

__global__ void k_embed(const int* __restrict__ x, const float* __restrict__ emb) {
  int i = blockIdx.x * 256 + threadIdx.x;        // N_NODESC*64 total
  int n = i >> 6, t = i & 63;
  if (n >= N_NODESC) return;
  float4 v = *(const float4*)(emb + (size_t)x[n] * DIM + t * 4);
  *(float4*)(g_hf + (size_t)n * DIM + t * 4) = v;
  u16x4 b = {f2bf(v.x), f2bf(v.y), f2bf(v.z), f2bf(v.w)};
  *(u16x4*)(g_hb + (size_t)n * DIM + t * 4) = b;
}

__global__ void k_count(const int* __restrict__ dst, const int* __restrict__ et) {
  int e = blockIdx.x * 256 + threadIdx.x;
  if (e >= N_EDGESC) return;
  atomicAdd(&g_cnt[dst[e] * 4 + et[e]], 1);
}

__global__ void k_scan1() {
  __shared__ int lds[256];
  int n = blockIdx.x * 256 + threadIdx.x;
  int deg = (n < N_NODESC) ? (g_cnt[n * 4] + g_cnt[n * 4 + 1] + g_cnt[n * 4 + 2]) : 0;
  lds[threadIdx.x] = deg;
  __syncthreads();
  for (int o = 128; o > 0; o >>= 1) {
    if (threadIdx.x < o) lds[threadIdx.x] += lds[threadIdx.x + o];
    __syncthreads();
  }
  if (threadIdx.x == 0) g_bsum[blockIdx.x] = lds[0];
}

__global__ void k_scan2() {
  __shared__ int lds[256];
  int t = threadIdx.x;
  int v = (t < 196) ? g_bsum[t] : 0;
  lds[t] = v;
  __syncthreads();
  for (int o = 1; o < 256; o <<= 1) {
    int u = (t >= o) ? lds[t - o] : 0;
    __syncthreads();
    lds[t] += u;
    __syncthreads();
  }
  if (t < 196) g_boff[t] = lds[t] - v;   // exclusive
}

__global__ void k_scan3() {
  __shared__ int lds[256];
  int n = blockIdx.x * 256 + threadIdx.x;
  int t = threadIdx.x;
  int deg = (n < N_NODESC) ? (g_cnt[n * 4] + g_cnt[n * 4 + 1] + g_cnt[n * 4 + 2]) : 0;
  lds[t] = deg;
  __syncthreads();
  for (int o = 1; o < 256; o <<= 1) {
    int u = (t >= o) ? lds[t - o] : 0;
    __syncthreads();
    lds[t] += u;
    __syncthreads();
  }
  if (n < N_NODESC) {
    int off = g_boff[blockIdx.x] + lds[t] - deg;
    g_rowoff[n] = off;
    g_cur[n] = off;
  }
  if (n == N_NODESC - 1) g_rowoff[N_NODESC] = g_boff[blockIdx.x] + lds[t];
}

__global__ void k_fill(const int* __restrict__ src, const int* __restrict__ dst,
                       const int* __restrict__ et) {
  int e = blockIdx.x * 256 + threadIdx.x;
  if (e >= N_EDGESC) return;
  int p = atomicAdd(&g_cur[dst[e]], 1);
  g_eidx[p] = (((unsigned)src[e]) << 2) | (unsigned)et[e];
}

__global__ void k_segoff(const int* __restrict__ seg) {
  int n = blockIdx.x * 256 + threadIdx.x;
  if (n >= N_NODESC) return;
  int g = seg[n];
  int gp = (n == 0) ? -1 : seg[n - 1];
  for (int t = gp + 1; t <= g; ++t) g_soff[t] = n;
  if (n == N_NODESC - 1)
    for (int t = g + 1; t <= NGRAPH; ++t) g_soff[t] = N_NODESC;
}

// ---------------- per-step kernels ----------------

#define ACC_ET(hv, et)                                                        \
  {                                                                           \
    float x0 = bf2f(hv[0]), x1 = bf2f(hv[1]), x2 = bf2f(hv[2]), x3 = bf2f(hv[3]); \
    if (et == 0)      { a0[0] += x0; a0[1] += x1; a0[2] += x2; a0[3] += x3; } \
    else if (et == 1) { a1[0] += x0; a1[1] += x1; a1[2] += x2; a1[3] += x3; } \
    else              { a2[0] += x0; a2[1] += x1; a2[2] += x2; a2[3] += x3; } \
  }

// p[n, e*256+d] = sum over in-edges of type e of h_bf16[src, d]; one wave per node.
// Edge loop unrolled x4 so 4 independent 512B gathers are in flight per wave.
__global__ __launch_bounds__(256) void k_agg() {
  int node = blockIdx.x * 4 + (threadIdx.x >> 6);
  int lane = threadIdx.x & 63;
  if (node >= N_NODESC) return;
  float a0[4] = {0.f, 0.f, 0.f, 0.f};
  float a1[4] = {0.f, 0.f, 0.f, 0.f};
  float a2[4] = {0.f, 0.f, 0.f, 0.f};
  int s = g_rowoff[node], e = g_rowoff[node + 1];
  int i = s;
  for (; i + 4 <= e; i += 4) {
    unsigned v0 = g_eidx[i], v1 = g_eidx[i + 1], v2 = g_eidx[i + 2], v3 = g_eidx[i + 3];
    u16x4 hv0 = *(const u16x4*)(g_hb + (size_t)(v0 >> 2) * DIM + lane * 4);
    u16x4 hv1 = *(const u16x4*)(g_hb + (size_t)(v1 >> 2) * DIM + lane * 4);
    u16x4 hv2 = *(const u16x4*)(g_hb + (size_t)(v2 >> 2) * DIM + lane * 4);
    u16x4 hv3 = *(const u16x4*)(g_hb + (size_t)(v3 >> 2) * DIM + lane * 4);
    int e0 = (int)(v0 & 3u), e1 = (int)(v1 & 3u), e2 = (int)(v2 & 3u), e3 = (int)(v3 & 3u);
    ACC_ET(hv0, e0);
    ACC_ET(hv1, e1);
    ACC_ET(hv2, e2);
    ACC_ET(hv3, e3);
  }
  for (; i < e; ++i) {
    unsigned v = g_eidx[i];
    u16x4 hv = *(const u16x4*)(g_hb + (size_t)(v >> 2) * DIM + lane * 4);
    int et = (int)(v & 3u);
    ACC_ET(hv, et);
  }
  size_t base = (size_t)node * DIM3 + lane * 4;
  u16x4 o0 = {f2bf(a0[0]), f2bf(a0[1]), f2bf(a0[2]), f2bf(a0[3])};
  u16x4 o1 = {f2bf(a1[0]), f2bf(a1[1]), f2bf(a1[2]), f2bf(a1[3])};
  u16x4 o2 = {f2bf(a2[0]), f2bf(a2[1]), f2bf(a2[2]), f2bf(a2[3])};
  *(u16x4*)(g_p + base)       = o0;
  *(u16x4*)(g_p + base + 256) = o1;
  *(u16x4*)(g_p + base + 512) = o2;
}

// MODE 0: g_a[bf16, NPADx256] = g_p[NPADx768] @ g_Wc^T + cnt*b_msg
// MODE 1: g_gi[f16, NPADx768] = g_a[NPADx256] @ g_WI^T + b_ih
// MODE 2: g_gh[f16, NPADx768] = g_hb[NPADx256] @ g_WH^T + b_hh
// BK=64 (128B LDS rows) + both-sides XOR swizzle (chunk ^= row&7):
// linear global_load_lds dest, inverse-swizzled global source, swizzled ds_read.
template <int MODE>
__global__ __launch_bounds__(256) void k_gemm(const float* __restrict__ bias,
                                              const float* __restrict__ bmsg) {
  constexpr int K  = (MODE == 0) ? DIM3 : DIM;
  constexpr int NC = (MODE == 0) ? DIM : DIM3;
  const unsigned short* __restrict__ A  = (MODE == 0) ? g_p  : (MODE == 1) ? g_a  : g_hb;
  const unsigned short* __restrict__ BT = (MODE == 0) ? g_Wc : (MODE == 1) ? g_WI : g_WH;

  __shared__ unsigned short lA[128 * 64];   // 16 KB
  __shared__ unsigned short lB[128 * 64];   // 16 KB
  const int tx = threadIdx.x;
  const int lane = tx & 63;
  const int wave = tx >> 6;
  const int wr = wave >> 1, wc = wave & 1;
  const int tileN = blockIdx.x * 128;
  const int tileM = blockIdx.y * 128;

  f32x4 acc[4][4];
#pragma unroll
  for (int m = 0; m < 4; ++m)
#pragma unroll
    for (int n = 0; n < 4; ++n) {
      acc[m][n][0] = 0.f; acc[m][n][1] = 0.f; acc[m][n][2] = 0.f; acc[m][n][3] = 0.f;
    }

  const int f  = lane & 15;
  const int q  = lane >> 4;      // 0..3
  const int xr = f & 7;          // read-side XOR

  // Per-thread staging slots (4 per tile): LDS dest linear in tx (wave-uniform
  // base + lane*16); global source chunk pre-swizzled so that physical slot s
  // of row r holds global chunk s ^ (r&7).
  int srow[4], scg[4];
#pragma unroll
  for (int i = 0; i < 4; ++i) {
    int byteo = i * 4096 + tx * 16;
    srow[i] = byteo >> 7;                       // 0..127
    scg[i] = ((byteo >> 4) & 7) ^ (srow[i] & 7);
  }

  for (int k0 = 0; k0 < K; k0 += 64) {
#pragma unroll
    for (int i = 0; i < 4; ++i) {
      int byteo = i * 4096 + tx * 16;
      async16((const void*)(A + (size_t)(tileM + srow[i]) * K + k0 + scg[i] * 8),
              (void*)((char*)lA + byteo));
      async16((const void*)(BT + (size_t)(tileN + srow[i]) * K + k0 + scg[i] * 8),
              (void*)((char*)lB + byteo));
    }
    __syncthreads();
#pragma unroll
    for (int kk = 0; kk < 2; ++kk) {
      short8 af[4], bfr[4];
#pragma unroll
      for (int m = 0; m < 4; ++m)
        af[m] = *(const short8*)((const char*)lA +
                 (wr * 64 + m * 16 + f) * 128 + (((kk * 4 + q) ^ xr) * 16));
#pragma unroll
      for (int n = 0; n < 4; ++n)
        bfr[n] = *(const short8*)((const char*)lB +
                 (wc * 64 + n * 16 + f) * 128 + (((kk * 4 + q) ^ xr) * 16));
#pragma unroll
      for (int m = 0; m < 4; ++m)
#pragma unroll
        for (int n = 0; n < 4; ++n)
          acc[m][n] = __builtin_amdgcn_mfma_f32_16x16x32_bf16(af[m], bfr[n], acc[m][n], 0, 0, 0);
    }
    __syncthreads();
  }

#pragma unroll
  for (int m = 0; m < 4; ++m) {
    int row0 = tileM + wr * 64 + m * 16 + q * 4;
#pragma unroll
    for (int n = 0; n < 4; ++n) {
      int col = tileN + wc * 64 + n * 16 + f;
      f32x4 v = acc[m][n];
#pragma unroll
      for (int r = 0; r < 4; ++r) {
        int row = row0 + r;
        float val = v[r];
        if (MODE == 0) {
          const int* c = g_cnt + (size_t)row * 4;
          val += c[0] * bmsg[col] + c[1] * bmsg[256 + col] + c[2] * bmsg[512 + col];
          g_a[(size_t)row * NC + col] = f2bf(val);
        } else if (MODE == 1) {
          val += bias[col];
          g_gi[(size_t)row * NC + col] = (_Float16)val;
        } else {
          val += bias[col];
          g_gh[(size_t)row * NC + col] = (_Float16)val;
        }
      }
    }
  }
}

// LAST=1 additionally computes the attention-gate logit for each node
// (each node occupies exactly one 64-lane wave; shuffle-reduce the dot).
template <int LAST>
__global__ void k_gru(const float* __restrict__ gw, const float* __restrict__ gb) {
  int i = blockIdx.x * 256 + threadIdx.x;   // N_NODESC*64
  int n = i >> 6, t = (i & 63) * 4;
  if (n >= N_NODESC) return;
  size_t b3 = (size_t)n * DIM3 + t;
  size_t b1 = (size_t)n * DIM + t;
  f16x4 ir4 = *(const f16x4*)(g_gi + b3);
  f16x4 iz4 = *(const f16x4*)(g_gi + b3 + 256);
  f16x4 in4 = *(const f16x4*)(g_gi + b3 + 512);
  f16x4 hr4 = *(const f16x4*)(g_gh + b3);
  f16x4 hz4 = *(const f16x4*)(g_gh + b3 + 256);
  f16x4 hn4 = *(const f16x4*)(g_gh + b3 + 512);
  float4 h = *(const float4*)(g_hf + b1);
  float4 o;
#pragma unroll
  for (int j = 0; j < 4; ++j) {
    float r = sigm((float)ir4[j] + (float)hr4[j]);
    float z = sigm((float)iz4[j] + (float)hz4[j]);
    float nn = tanhf((float)in4[j] + r * (float)hn4[j]);
    float hj = (j == 0) ? h.x : (j == 1) ? h.y : (j == 2) ? h.z : h.w;
    float oj = (1.f - z) * nn + z * hj;
    if (j == 0) o.x = oj; else if (j == 1) o.y = oj; else if (j == 2) o.z = oj; else o.w = oj;
  }
  *(float4*)(g_hf + b1) = o;
  u16x4 ob = {f2bf(o.x), f2bf(o.y), f2bf(o.z), f2bf(o.w)};
  *(u16x4*)(g_hb + b1) = ob;
  if (LAST) {
    float4 w = *(const float4*)(gw + t);
    float p = o.x * w.x + o.y * w.y + o.z * w.z + o.w * w.w;
    for (int off = 32; off > 0; off >>= 1) p += __shfl_xor(p, off);
    if ((threadIdx.x & 63) == 0) g_gate[n] = p + gb[0];
  }
}

// ---------------- pooling ----------------

// Per-graph softmax max + denom (gate array is only 200 KB; 64 blocks).
__global__ void k_segred() {
  int g = blockIdx.x, t = threadIdx.x;
  __shared__ float red[256];
  int s = g_soff[g], e = g_soff[g + 1];
  float m = -3.4e38f;
  for (int n = s + t; n < e; n += 256) m = fmaxf(m, g_gate[n]);
  red[t] = m;
  __syncthreads();
  for (int o = 128; o > 0; o >>= 1) {
    if (t < o) red[t] = fmaxf(red[t], red[t + o]);
    __syncthreads();
  }
  m = red[0];
  __syncthreads();
  float sm = 0.f;
  for (int n = s + t; n < e; n += 256) sm += expf(g_gate[n] - m);
  red[t] = sm;
  __syncthreads();
  for (int o = 128; o > 0; o >>= 1) {
    if (t < o) red[t] += red[t + o];
    __syncthreads();
  }
  if (t == 0) {
    g_gmax[g] = m;
    g_gden[g] = (e > s && red[0] != 0.f) ? red[0] : 1.f;
  }
}

__global__ void k_zero_out(float* __restrict__ out) {
  out[blockIdx.x * 256 + threadIdx.x] = 0.f;   // 64*256 = NGRAPH*DIM
}

// 391 blocks x 128 nodes; thread t owns output dim t. seg_ids sorted ->
// accumulate and flush on graph boundary with one atomicAdd per (block,graph).
__global__ __launch_bounds__(256) void k_poolacc(const int* __restrict__ seg,
                                                 float* __restrict__ out) {
  __shared__ int   segL[128];
  __shared__ float alphaL[128];
  int base = blockIdx.x * 128;
  int t = threadIdx.x;
  if (t < 128) {
    int n = base + t;
    if (n < N_NODESC) {
      int g = seg[n];
      segL[t] = g;
      alphaL[t] = expf(g_gate[n] - g_gmax[g]) / g_gden[g];
    } else {
      segL[t] = -1;
    }
  }
  __syncthreads();
  float acc = 0.f;
  int gcur = segL[0];
  for (int j = 0; j < 128; ++j) {
    int gs = segL[j];
    if (gs < 0) break;
    if (gs != gcur) {
      atomicAdd(out + (size_t)gcur * DIM + t, acc);
      acc = 0.f;
      gcur = gs;
    }
    acc += alphaL[j] * g_hf[(size_t)(base + j) * DIM + t];
  }
  if (gcur >= 0) atomicAdd(out + (size_t)gcur * DIM + t, acc);
}

// ---------------- launch ----------------

extern "C" void kernel_launch(void* const* d_in, const int* in_sizes, int n_in,
                              void* d_out, int out_size, void* d_ws, size_t ws_size,
                              hipStream_t stream) {
  const int* x = (const int*)d_in[0];
  const int* src = (const int*)d_in[1];
  const int* dst = (const int*)d_in[2];
  const int* ety = (const int*)d_in[3];
  const int* seg = (const int*)d_in[4];
  const float* emb = (const float*)d_in[6];
  const float* Wmsg = (const float*)d_in[7];
  const float* bmsg = (const float*)d_in[8];
  const float* wih = (const float*)d_in[9];
  const float* whh = (const float*)d_in[10];
  const float* bih = (const float*)d_in[11];
  const float* bhh = (const float*)d_in[12];
  const float* gw = (const float*)d_in[13];
  const float* gb = (const float*)d_in[14];
  float* out = (float*)d_out;

  k_zero_cnt<<<NPAD * 4 / 256, 256, 0, stream>>>();
  k_prep_w<<<2304, 256, 0, stream>>>(Wmsg, wih, whh);
  k_embed<<<12500, 256, 0, stream>>>(x, emb);
  k_count<<<(N_EDGESC + 255) / 256, 256, 0, stream>>>(dst, ety);
  k_scan1<<<196, 256, 0, stream>>>();
  k_scan2<<<1, 256, 0, stream>>>();
  k_scan3<<<196, 256, 0, stream>>>();
  k_fill<<<(N_EDGESC + 255) / 256, 256, 0, stream>>>(src, dst, ety);
  k_segoff<<<196, 256, 0, stream>>>(seg);

  for (int s = 0; s < NSTEPS; ++s) {
    k_agg<<<12500, 256, 0, stream>>>();
    k_gemm<0><<<dim3(2, 391), 256, 0, stream>>>(nullptr, bmsg);
    k_gemm<1><<<dim3(6, 391), 256, 0, stream>>>(bih, nullptr);
    k_gemm<2><<<dim3(6, 391), 256, 0, stream>>>(bhh, nullptr);
    if (s < NSTEPS - 1)
      k_gru<0><<<12500, 256, 0, stream>>>(nullptr, nullptr);
    else
      k_gru<1><<<12500, 256, 0, stream>>>(gw, gb);
  }

  k_segred<<<NGRAPH, 256, 0, stream>>>();
  k_zero_out<<<NGRAPH, 256, 0, stream>>>(out);
  k_poolacc<<<391, 256, 0, stream>>>(seg, out);
}